// Round 4
// baseline (1262.209 us; speedup 1.0000x reference)
//
#include <hip/hip_runtime.h>
#include <math.h>

#define BB 2
#define LL 2048
#define DMODEL 256
#define NH 8
#define DHEAD 32
#define LL2 (LL*LL)            // 4,194,304 floats per (b,h) attn slab
#define NQ (BB*NH*LL*DHEAD)    // 1,048,576 floats per Q/K/V/ctx tensor

constexpr float SCALE_INV = 0.17677669529663687f;  // 1/sqrt(32)

// ---------------- Kernel 1: QKV projections ----------------
__global__ __launch_bounds__(256) void proj_kernel(
    const float* __restrict__ xq, const float* __restrict__ xk, const float* __restrict__ xv,
    const float* __restrict__ Wq, const float* __restrict__ Wk, const float* __restrict__ Wv,
    float* __restrict__ Qo, float* __restrict__ Ko, float* __restrict__ Vo,
    float* __restrict__ Q15, float* __restrict__ K15)
{
    const float* X; const float* W; float* O; float* dup;
    if (blockIdx.z == 0)      { X = xq; W = Wq; O = Qo; dup = Q15; }
    else if (blockIdx.z == 1) { X = xk; W = Wk; O = Ko; dup = K15; }
    else                      { X = xv; W = Wv; O = Vo; dup = nullptr; }

    __shared__ float Xs[64][33];
    __shared__ float Ws[64][33];

    const int t  = threadIdx.x;
    const int m0 = blockIdx.x * 64;
    const int n0 = blockIdx.y * 64;
    const int ty = t >> 4;
    const int tx = t & 15;

    float acc[4][4] = {};

    for (int k0 = 0; k0 < DMODEL; k0 += 32) {
#pragma unroll
        for (int r = 0; r < 2; ++r) {
            int f   = t + 256 * r;
            int row = f >> 3;
            int c   = (f & 7) << 2;
            float4 xv4 = *(const float4*)(X + (size_t)(m0 + row) * DMODEL + k0 + c);
            Xs[row][c+0] = xv4.x; Xs[row][c+1] = xv4.y; Xs[row][c+2] = xv4.z; Xs[row][c+3] = xv4.w;
            float4 wv4 = *(const float4*)(W + (size_t)(n0 + row) * DMODEL + k0 + c);
            Ws[row][c+0] = wv4.x; Ws[row][c+1] = wv4.y; Ws[row][c+2] = wv4.z; Ws[row][c+3] = wv4.w;
        }
        __syncthreads();
#pragma unroll
        for (int kk = 0; kk < 32; ++kk) {
            float a[4], bv[4];
#pragma unroll
            for (int i = 0; i < 4; ++i) a[i]  = Xs[ty*4+i][kk];
#pragma unroll
            for (int j = 0; j < 4; ++j) bv[j] = Ws[tx*4+j][kk];
#pragma unroll
            for (int i = 0; i < 4; ++i)
#pragma unroll
                for (int j = 0; j < 4; ++j)
                    acc[i][j] = fmaf(a[i], bv[j], acc[i][j]);
        }
        __syncthreads();
    }

#pragma unroll
    for (int i = 0; i < 4; ++i) {
        int row = m0 + ty*4 + i;
        int b   = row / LL;
        int l   = row % LL;
#pragma unroll
        for (int j = 0; j < 4; ++j) {
            int col = n0 + tx*4 + j;
            int h   = col >> 5;
            int d   = col & 31;
            O[(size_t)(((b*NH + h)*LL) + l) * DHEAD + d] = acc[i][j];
            if (dup && row >= LL && col >= 224) {
                dup[(size_t)(row - LL) * DHEAD + (col - 224)] = acc[i][j];
            }
        }
    }
}

// ---------------- Kernel 2: pure flash pass (NO attn store) ----------------
// One block per (b,h, 32-row q tile); 32 k-tiles of 64. Produces ctx + M/S
// stats only. v5: the 251 MB raw-logit store is GONE — attn values are
// produced once, by attn_final_kernel / attn15_kernel recompute (the attn
// matrix was previously touched 3x in HBM: store, re-read, re-write).
__global__ __launch_bounds__(256, 3) void attn_main_kernel(
    const float* __restrict__ Q, const float* __restrict__ K, const float* __restrict__ V,
    const int* __restrict__ mask, const float* __restrict__ adj, const float* __restrict__ dist,
    const float* __restrict__ wA, const float* __restrict__ wD,
    float* __restrict__ ctx,
    float* __restrict__ Mall, float* __restrict__ Sall,
    float* __restrict__ Mw, float* __restrict__ Sw)
{
    const int t    = threadIdx.x;
    const int bh   = blockIdx.y;
    const int b    = bh >> 3;
    const int h    = bh & 7;
    const int q0   = blockIdx.x * 32;
    const int kcol = t & 63;
    const int wid  = t >> 6;
    const int dcol = t & 31;
    const int grp  = t >> 5;

    __shared__ float Qs[32][36];
    __shared__ float Ks[64][36];
    __shared__ float Vs[64][36];
    __shared__ float As[32][68];   // 0..63 = p; 64 = alpha; 65 = invS

    const float wa = wA[h];
    const float wd = wD[h];

    {   // Q tile 32x32
        int row = t >> 3;
        int c   = (t & 7) << 2;
        float4 qv = *(const float4*)(Q + (size_t)(bh * LL + q0 + row) * DHEAD + c);
        Qs[row][c+0] = qv.x; Qs[row][c+1] = qv.y; Qs[row][c+2] = qv.z; Qs[row][c+3] = qv.w;
    }

    float m[8], s[8];
#pragma unroll
    for (int j = 0; j < 8; ++j) { m[j] = -INFINITY; s[j] = 0.0f; }
    float acc[4] = {0.f, 0.f, 0.f, 0.f};

    const size_t kv_base = (size_t)bh * LL * DHEAD;
    const size_t mrow    = (size_t)(b * LL + q0);   // base row in mask-class tensors

    // prefetch tile 0's fused mask/adj/dist multiplier (1 reg per row)
    float fm[8];
#pragma unroll
    for (int j = 0; j < 8; ++j) {
        size_t mi = (mrow + wid + 4*j) * LL + kcol;
        int   mk = mask[mi];
        float a  = adj[mi];
        float d  = dist[mi];
        fm[j] = (mk == 1) ? (1.0f + a*wa + d*wd) : 0.0f;
    }

    for (int kt = 0; kt < 32; ++kt) {
        // stage K,V tile (64 x 32)
#pragma unroll
        for (int r = 0; r < 2; ++r) {
            int f   = t + 256 * r;
            int row = f >> 3;
            int c   = (f & 7) << 2;
            float4 kv = *(const float4*)(K + kv_base + (size_t)(kt*64 + row) * DHEAD + c);
            Ks[row][c+0]=kv.x; Ks[row][c+1]=kv.y; Ks[row][c+2]=kv.z; Ks[row][c+3]=kv.w;
            float4 vv = *(const float4*)(V + kv_base + (size_t)(kt*64 + row) * DHEAD + c);
            Vs[row][c+0]=vv.x; Vs[row][c+1]=vv.y; Vs[row][c+2]=vv.z; Vs[row][c+3]=vv.w;
        }
        __syncthreads();

        float4 kf[8];
        {
            const float4* kp = (const float4*)&Ks[kcol][0];
#pragma unroll
            for (int c = 0; c < 8; ++c) kf[c] = kp[c];
        }

        float lv[8];
#pragma unroll
        for (int j = 0; j < 8; ++j) {
            int qq = wid + 4*j;
            float s0 = 0.f;
            const float4* qp = (const float4*)&Qs[qq][0];
#pragma unroll
            for (int c = 0; c < 8; ++c) {
                float4 q4 = qp[c];
                s0 += q4.x*kf[c].x + q4.y*kf[c].y + q4.z*kf[c].z + q4.w*kf[c].w;
            }
            lv[j] = s0 * fm[j] * SCALE_INV;
        }

        // 8 independent max butterflies
        float mloc[8];
#pragma unroll
        for (int j = 0; j < 8; ++j) mloc[j] = lv[j];
#pragma unroll
        for (int off = 1; off < 64; off <<= 1)
#pragma unroll
            for (int j = 0; j < 8; ++j)
                mloc[j] = fmaxf(mloc[j], __shfl_xor(mloc[j], off, 64));

#pragma unroll
        for (int j = 0; j < 8; ++j) {
            int qq = wid + 4*j;
            float mnew  = fmaxf(m[j], mloc[j]);
            float alpha = __expf(m[j] - mnew);
            float p     = __expf(lv[j] - mnew);
            s[j] = s[j]*alpha + p;         // per-lane partial sum
            m[j] = mnew;
            As[qq][kcol] = p;
            if (kcol == 0) As[qq][64] = alpha;
        }
        __syncthreads();

        // prefetch next tile's fused multiplier while PV runs
        if (kt + 1 < 32) {
            const int kgn = (kt+1)*64 + kcol;
#pragma unroll
            for (int j = 0; j < 8; ++j) {
                size_t mi = (mrow + wid + 4*j) * LL + kgn;
                int   mk = mask[mi];
                float a  = adj[mi];
                float d  = dist[mi];
                fm[j] = (mk == 1) ? (1.0f + a*wa + d*wd) : 0.0f;
            }
        }

        // PV: thread (grp,dcol) accumulates rows grp*4..+3, d = dcol
        float sum[4] = {0.f, 0.f, 0.f, 0.f};
#pragma unroll
        for (int c = 0; c < 16; ++c) {
            int kl = c * 4;
            float v0 = Vs[kl+0][dcol];
            float v1 = Vs[kl+1][dcol];
            float v2 = Vs[kl+2][dcol];
            float v3 = Vs[kl+3][dcol];
#pragma unroll
            for (int jj = 0; jj < 4; ++jj) {
                float4 a4 = *(const float4*)&As[grp*4+jj][kl];
                sum[jj] += a4.x*v0 + a4.y*v1 + a4.z*v2 + a4.w*v3;
            }
        }
#pragma unroll
        for (int jj = 0; jj < 4; ++jj) {
            int r = grp*4 + jj;
            acc[jj] = acc[jj]*As[r][64] + sum[jj];
        }
        __syncthreads();
    }

    // epilogue: one sum butterfly per row; stats out; ctx scale
#pragma unroll
    for (int j = 0; j < 8; ++j) {
        float ss = s[j];
#pragma unroll
        for (int off = 1; off < 64; off <<= 1)
            ss += __shfl_xor(ss, off, 64);
        float inv = 1.0f / ss;
        int qq = wid + 4*j;
        int qg = q0 + qq;
        if (kcol == 0) {
            As[qq][65] = inv;
            if (bh != 15) { Mall[bh*LL + qg] = m[j]; Sall[bh*LL + qg] = inv; }
            else          { Mw[qg] = m[j];           Sw[qg] = inv; }
        }
    }
    __syncthreads();

#pragma unroll
    for (int jj = 0; jj < 4; ++jj) {
        int r  = grp*4 + jj;
        int qg = q0 + r;
        ctx[(size_t)(bh * LL + qg) * DHEAD + dcol] = acc[jj] * As[r][65];
    }
}

// ---------------- Kernel 3: attn finalize for bh 0..14 — recompute + single write ----
// Generalized attn15: grid (64, 8, 15). Reads Qw/Kw (L2-resident), M/S stats,
// recomputes logits with the exact expression shapes of attn_main, writes the
// final softmax value ONCE. Replaces the store->re-read->re-write rescale path.
__global__ __launch_bounds__(256) void attn_final_kernel(
    const float* __restrict__ Q, const float* __restrict__ K,
    const int* __restrict__ mask, const float* __restrict__ adj, const float* __restrict__ dist,
    const float* __restrict__ wA, const float* __restrict__ wD,
    const float* __restrict__ Mall, const float* __restrict__ Sall,
    float* __restrict__ attn)
{
    const int t    = threadIdx.x;
    const int bh   = blockIdx.z;          // 0..14
    const int b    = bh >> 3;
    const int h    = bh & 7;
    const int q0   = blockIdx.x * 32;
    const int kt0  = blockIdx.y * 2;
    const int kcol = t & 63;
    const int wid  = t >> 6;

    __shared__ float Qs[32][36];
    __shared__ float Ks[128][36];

    const float wa = wA[h];
    const float wd = wD[h];

    const size_t qk_base = (size_t)bh * LL * DHEAD;
    float* aout = attn + (size_t)bh * LL2;

    {
        int row = t >> 3;
        int c   = (t & 7) << 2;
        float4 qv = *(const float4*)(Q + qk_base + (size_t)(q0 + row) * DHEAD + c);
        Qs[row][c+0] = qv.x; Qs[row][c+1] = qv.y; Qs[row][c+2] = qv.z; Qs[row][c+3] = qv.w;
    }

    float Mr[8], Sr[8];
#pragma unroll
    for (int j = 0; j < 8; ++j) {
        int qg = q0 + wid + 4*j;
        Mr[j] = Mall[bh*LL + qg];
        Sr[j] = Sall[bh*LL + qg];
    }

    for (int kt = kt0; kt < kt0 + 2; ++kt) {
#pragma unroll
        for (int r = 0; r < 4; ++r) {
            int f   = t + 256 * r;
            int row = f >> 3;
            int c   = (f & 7) << 2;
            float4 kv = *(const float4*)(K + qk_base + (size_t)(kt*128 + row) * DHEAD + c);
            Ks[row][c+0]=kv.x; Ks[row][c+1]=kv.y; Ks[row][c+2]=kv.z; Ks[row][c+3]=kv.w;
        }
        __syncthreads();

        float4 k0[8], k1[8];
        {
            const float4* p0 = (const float4*)&Ks[kcol][0];
            const float4* p1 = (const float4*)&Ks[kcol + 64][0];
#pragma unroll
            for (int c = 0; c < 8; ++c) { k0[c] = p0[c]; k1[c] = p1[c]; }
        }

        const int kg0 = kt*128 + kcol;
#pragma unroll
        for (int j = 0; j < 8; ++j) {
            int qq = wid + 4*j;
            float s0 = 0.f, s1 = 0.f;
            const float4* qp = (const float4*)&Qs[qq][0];
#pragma unroll
            for (int c = 0; c < 8; ++c) {
                float4 q4 = qp[c];
                s0 += q4.x*k0[c].x + q4.y*k0[c].y + q4.z*k0[c].z + q4.w*k0[c].w;
                s1 += q4.x*k1[c].x + q4.y*k1[c].y + q4.z*k1[c].z + q4.w*k1[c].w;
            }
            int qg = q0 + qq;
            size_t mi0 = (size_t)(b * LL + qg) * LL + kg0;
            size_t mi1 = mi0 + 64;
            float fm0 = (mask[mi0] == 1) ? (1.0f + adj[mi0]*wa + dist[mi0]*wd) : 0.0f;
            float fm1 = (mask[mi1] == 1) ? (1.0f + adj[mi1]*wa + dist[mi1]*wd) : 0.0f;
            float l0 = s0 * fm0 * SCALE_INV;
            float l1 = s1 * fm1 * SCALE_INV;
            size_t ai = (size_t)qg * LL + kg0;
            aout[ai]      = __expf(l0 - Mr[j]) * Sr[j];
            aout[ai + 64] = __expf(l1 - Mr[j]) * Sr[j];
        }
        __syncthreads();
    }
}

// ---------------- Kernel 4: output projection ----------------
__global__ __launch_bounds__(256) void out_gemm_kernel(
    const float* __restrict__ ctx, const float* __restrict__ Wo, float* __restrict__ Y)
{
    __shared__ float Xs[64][33];
    __shared__ float Ws[64][33];

    const int t  = threadIdx.x;
    const int m0 = blockIdx.x * 64;
    const int n0 = blockIdx.y * 64;
    const int ty = t >> 4;
    const int tx = t & 15;

    float acc[4][4] = {};

    for (int kt = 0; kt < 8; ++kt) {
#pragma unroll
        for (int r = 0; r < 2; ++r) {
            int f   = t + 256*r;
            int row = f >> 3;
            int c   = (f & 7) << 2;
            int grow = m0 + row;
            int b = grow / LL, l = grow % LL;
            float4 xv4 = *(const float4*)(ctx + (size_t)((b*NH + kt)*LL + l) * DHEAD + c);
            Xs[row][c+0]=xv4.x; Xs[row][c+1]=xv4.y; Xs[row][c+2]=xv4.z; Xs[row][c+3]=xv4.w;
            float4 wv4 = *(const float4*)(Wo + (size_t)(n0 + row) * DMODEL + kt*32 + c);
            Ws[row][c+0]=wv4.x; Ws[row][c+1]=wv4.y; Ws[row][c+2]=wv4.z; Ws[row][c+3]=wv4.w;
        }
        __syncthreads();
#pragma unroll
        for (int kk = 0; kk < 32; ++kk) {
            float a[4], bv[4];
#pragma unroll
            for (int i = 0; i < 4; ++i) a[i]  = Xs[ty*4+i][kk];
#pragma unroll
            for (int j = 0; j < 4; ++j) bv[j] = Ws[tx*4+j][kk];
#pragma unroll
            for (int i = 0; i < 4; ++i)
#pragma unroll
                for (int j = 0; j < 4; ++j)
                    acc[i][j] = fmaf(a[i], bv[j], acc[i][j]);
        }
        __syncthreads();
    }

#pragma unroll
    for (int i = 0; i < 4; ++i) {
        int row = m0 + ty*4 + i;
#pragma unroll
        for (int j = 0; j < 4; ++j) {
            int col = n0 + tx*4 + j;
            Y[(size_t)row * DMODEL + col] = acc[i][j];
        }
    }
}

// ---------------- Kernel 5: attn writes for bh==15, split-k ----------------
// grid (64, 8): q-tile x, k-range y (2 tiles of 128 each). Runs LAST (clobbers
// the Qw/Kw/Vw/Cw scratch parked in the bh=15 slab); reads the ws duplicates.
__global__ __launch_bounds__(256) void attn15_kernel(
    const float* __restrict__ Q15, const float* __restrict__ K15,
    const int* __restrict__ mask, const float* __restrict__ adj, const float* __restrict__ dist,
    const float* __restrict__ wA, const float* __restrict__ wD,
    const float* __restrict__ Mw, const float* __restrict__ Sw,
    float* __restrict__ attn15)
{
    const int t    = threadIdx.x;
    const int q0   = blockIdx.x * 32;
    const int kt0  = blockIdx.y * 2;
    const int kcol = t & 63;
    const int wid  = t >> 6;

    __shared__ float Qs[32][36];
    __shared__ float Ks[128][36];

    const float wa = wA[7];
    const float wd = wD[7];

    {
        int row = t >> 3;
        int c   = (t & 7) << 2;
        float4 qv = *(const float4*)(Q15 + (size_t)(q0 + row) * DHEAD + c);
        Qs[row][c+0] = qv.x; Qs[row][c+1] = qv.y; Qs[row][c+2] = qv.z; Qs[row][c+3] = qv.w;
    }

    float Mr[8], Sr[8];
#pragma unroll
    for (int j = 0; j < 8; ++j) {
        int qg = q0 + wid + 4*j;
        Mr[j] = Mw[qg];
        Sr[j] = Sw[qg];
    }

    for (int kt = kt0; kt < kt0 + 2; ++kt) {
#pragma unroll
        for (int r = 0; r < 4; ++r) {
            int f   = t + 256 * r;
            int row = f >> 3;
            int c   = (f & 7) << 2;
            float4 kv = *(const float4*)(K15 + (size_t)(kt*128 + row) * DHEAD + c);
            Ks[row][c+0]=kv.x; Ks[row][c+1]=kv.y; Ks[row][c+2]=kv.z; Ks[row][c+3]=kv.w;
        }
        __syncthreads();

        float4 k0[8], k1[8];
        {
            const float4* p0 = (const float4*)&Ks[kcol][0];
            const float4* p1 = (const float4*)&Ks[kcol + 64][0];
#pragma unroll
            for (int c = 0; c < 8; ++c) { k0[c] = p0[c]; k1[c] = p1[c]; }
        }

        const int kg0 = kt*128 + kcol;
#pragma unroll
        for (int j = 0; j < 8; ++j) {
            int qq = wid + 4*j;
            float s0 = 0.f, s1 = 0.f;
            const float4* qp = (const float4*)&Qs[qq][0];
#pragma unroll
            for (int c = 0; c < 8; ++c) {
                float4 q4 = qp[c];
                s0 += q4.x*k0[c].x + q4.y*k0[c].y + q4.z*k0[c].z + q4.w*k0[c].w;
                s1 += q4.x*k1[c].x + q4.y*k1[c].y + q4.z*k1[c].z + q4.w*k1[c].w;
            }
            int qg = q0 + qq;
            size_t mi0 = (size_t)(LL + qg) * LL + kg0;      // b = 1
            size_t mi1 = mi0 + 64;
            float sm0 = (mask[mi0] == 1) ? s0 : 0.0f;
            float sm1 = (mask[mi1] == 1) ? s1 : 0.0f;
            float l0 = sm0 * (1.0f + adj[mi0]*wa + dist[mi0]*wd) * SCALE_INV;
            float l1 = sm1 * (1.0f + adj[mi1]*wa + dist[mi1]*wd) * SCALE_INV;
            size_t ai = (size_t)qg * LL + kg0;
            attn15[ai]      = __expf(l0 - Mr[j]) * Sr[j];
            attn15[ai + 64] = __expf(l1 - Mr[j]) * Sr[j];
        }
        __syncthreads();
    }
}

extern "C" void kernel_launch(void* const* d_in, const int* in_sizes, int n_in,
                              void* d_out, int out_size, void* d_ws, size_t ws_size,
                              hipStream_t stream)
{
    const float* q    = (const float*)d_in[0];
    const float* k    = (const float*)d_in[1];
    const float* v    = (const float*)d_in[2];
    const int*   mask = (const int*)d_in[3];
    const float* adj  = (const float*)d_in[4];
    const float* dist = (const float*)d_in[5];
    const float* Wq   = (const float*)d_in[6];
    const float* Wk   = (const float*)d_in[7];
    const float* Wv   = (const float*)d_in[8];
    const float* Wo   = (const float*)d_in[9];
    const float* wA   = (const float*)d_in[10];
    const float* wD   = (const float*)d_in[11];

    float* out  = (float*)d_out;                       // B*L*DM = 1,048,576 floats
    float* attn = out + (size_t)BB*LL*DMODEL;          // B*H*L*L

    // Scratch parked in attn[bh=15]'s slab (4*NQ floats = 16 MB, dead until attn15).
    float* tail = attn + (size_t)15 * LL2;
    float* Qw = tail;
    float* Kw = tail + (size_t)NQ;
    float* Vw = tail + (size_t)2 * NQ;
    float* Cw = tail + (size_t)3 * NQ;

    // Softmax stats (bh<15) parked in `out` (dead until out_gemm; attn_final
    // consumes them BEFORE out_gemm runs).
    float* Mall = out;                 // 15*2048 floats
    float* Sall = out + 32768;         // 15*2048 floats

    // Tiny ws: bh=15 Q/K slices + bh=15 stats (528 KB).
    float* Q15 = (float*)d_ws;
    float* K15 = Q15 + (size_t)LL * DHEAD;
    float* Mw  = K15 + (size_t)LL * DHEAD;
    float* Sw  = Mw + LL;

    dim3 g1(64, 4, 3);
    proj_kernel<<<g1, 256, 0, stream>>>(q, k, v, Wq, Wk, Wv, Qw, Kw, Vw, Q15, K15);

    dim3 g2(LL/32, BB*NH);
    attn_main_kernel<<<g2, 256, 0, stream>>>(Qw, Kw, Vw, mask, adj, dist, wA, wD,
                                             Cw, Mall, Sall, Mw, Sw);

    // bh<15 attn: recompute + single write (reads Qw/Kw + Mall/Sall in `out`)
    dim3 gf(64, 8, 15);
    attn_final_kernel<<<gf, 256, 0, stream>>>(Qw, Kw, mask, adj, dist, wA, wD,
                                              Mall, Sall, attn);

    // out projection (overwrites `out`, consumes Cw)
    dim3 g3(64, 4);
    out_gemm_kernel<<<g3, 256, 0, stream>>>(Cw, Wo, out);

    // bh=15 attn last (clobbers scratch slab; reads ws duplicates)
    dim3 g4(64, 8);
    attn15_kernel<<<g4, 256, 0, stream>>>(Q15, K15, mask, adj, dist, wA, wD, Mw, Sw,
                                          attn + (size_t)15 * LL2);
}

// Round 5
// 1252.178 us; speedup vs baseline: 1.0080x; 1.0080x over previous
//
#include <hip/hip_runtime.h>
#include <math.h>

#define BB 2
#define LL 2048
#define DMODEL 256
#define NH 8
#define DHEAD 32
#define LL2 (LL*LL)            // 4,194,304 floats per (b,h) attn slab
#define NQ (BB*NH*LL*DHEAD)    // 1,048,576 floats per Q/K/V/ctx tensor

constexpr float SCALE_INV = 0.17677669529663687f;  // 1/sqrt(32)

// ---------------- Kernel 1: QKV projections ----------------
__global__ __launch_bounds__(256) void proj_kernel(
    const float* __restrict__ xq, const float* __restrict__ xk, const float* __restrict__ xv,
    const float* __restrict__ Wq, const float* __restrict__ Wk, const float* __restrict__ Wv,
    float* __restrict__ Qo, float* __restrict__ Ko, float* __restrict__ Vo,
    float* __restrict__ Q15, float* __restrict__ K15)
{
    const float* X; const float* W; float* O; float* dup;
    if (blockIdx.z == 0)      { X = xq; W = Wq; O = Qo; dup = Q15; }
    else if (blockIdx.z == 1) { X = xk; W = Wk; O = Ko; dup = K15; }
    else                      { X = xv; W = Wv; O = Vo; dup = nullptr; }

    __shared__ float Xs[64][33];
    __shared__ float Ws[64][33];

    const int t  = threadIdx.x;
    const int m0 = blockIdx.x * 64;
    const int n0 = blockIdx.y * 64;
    const int ty = t >> 4;
    const int tx = t & 15;

    float acc[4][4] = {};

    for (int k0 = 0; k0 < DMODEL; k0 += 32) {
#pragma unroll
        for (int r = 0; r < 2; ++r) {
            int f   = t + 256 * r;
            int row = f >> 3;
            int c   = (f & 7) << 2;
            float4 xv4 = *(const float4*)(X + (size_t)(m0 + row) * DMODEL + k0 + c);
            Xs[row][c+0] = xv4.x; Xs[row][c+1] = xv4.y; Xs[row][c+2] = xv4.z; Xs[row][c+3] = xv4.w;
            float4 wv4 = *(const float4*)(W + (size_t)(n0 + row) * DMODEL + k0 + c);
            Ws[row][c+0] = wv4.x; Ws[row][c+1] = wv4.y; Ws[row][c+2] = wv4.z; Ws[row][c+3] = wv4.w;
        }
        __syncthreads();
#pragma unroll
        for (int kk = 0; kk < 32; ++kk) {
            float a[4], bv[4];
#pragma unroll
            for (int i = 0; i < 4; ++i) a[i]  = Xs[ty*4+i][kk];
#pragma unroll
            for (int j = 0; j < 4; ++j) bv[j] = Ws[tx*4+j][kk];
#pragma unroll
            for (int i = 0; i < 4; ++i)
#pragma unroll
                for (int j = 0; j < 4; ++j)
                    acc[i][j] = fmaf(a[i], bv[j], acc[i][j]);
        }
        __syncthreads();
    }

#pragma unroll
    for (int i = 0; i < 4; ++i) {
        int row = m0 + ty*4 + i;
        int b   = row / LL;
        int l   = row % LL;
#pragma unroll
        for (int j = 0; j < 4; ++j) {
            int col = n0 + tx*4 + j;
            int h   = col >> 5;
            int d   = col & 31;
            O[(size_t)(((b*NH + h)*LL) + l) * DHEAD + d] = acc[i][j];
            if (dup && row >= LL && col >= 224) {
                dup[(size_t)(row - LL) * DHEAD + (col - 224)] = acc[i][j];
            }
        }
    }
}

// ---------------- Kernel 2: pure flash pass (NO attn store) ----------------
// v6 (occupancy): QBLK 32 -> 16. Grid doubles to 2048 blocks; LDS drops to
// ~24.5 KB -> 6 blocks/CU (24 waves/CU vs 16 before), per-block critical path
// halves. R4 showed latency/convoy-bound (VALUBusy 32%, HBM 2%, occupancy 25%):
// 3 barriers/tile with serial shfl/exp/L2-latency chains and too few waves to
// cover them. launch_bounds(256,6) caps VGPR ~85 so 6 blocks/CU are possible —
// per-thread state halved (fm[4], m/s[4], acc[2]) so no spill expected
// (tripwire: WRITE_SIZE must stay ~4 MB).
__global__ __launch_bounds__(256, 6) void attn_main_kernel(
    const float* __restrict__ Q, const float* __restrict__ K, const float* __restrict__ V,
    const int* __restrict__ mask, const float* __restrict__ adj, const float* __restrict__ dist,
    const float* __restrict__ wA, const float* __restrict__ wD,
    float* __restrict__ ctx,
    float* __restrict__ Mall, float* __restrict__ Sall,
    float* __restrict__ Mw, float* __restrict__ Sw)
{
    const int t    = threadIdx.x;
    const int bh   = blockIdx.y;
    const int b    = bh >> 3;
    const int h    = bh & 7;
    const int q0   = blockIdx.x * 16;
    const int kcol = t & 63;
    const int wid  = t >> 6;          // 0..3
    const int dcol = t & 31;
    const int grp  = t >> 5;          // 0..7

    __shared__ float Qs[16][36];
    __shared__ float Ks[64][36];
    __shared__ float Vs[64][36];
    __shared__ float As[16][68];   // 0..63 = p; 64 = alpha; 65 = invS

    const float wa = wA[h];
    const float wd = wD[h];

    if (t < 128) {   // Q tile 16x32
        int row = t >> 3;
        int c   = (t & 7) << 2;
        float4 qv = *(const float4*)(Q + (size_t)(bh * LL + q0 + row) * DHEAD + c);
        Qs[row][c+0] = qv.x; Qs[row][c+1] = qv.y; Qs[row][c+2] = qv.z; Qs[row][c+3] = qv.w;
    }

    float m[4], s[4];
#pragma unroll
    for (int j = 0; j < 4; ++j) { m[j] = -INFINITY; s[j] = 0.0f; }
    float acc[2] = {0.f, 0.f};

    const size_t kv_base = (size_t)bh * LL * DHEAD;
    const size_t mrow    = (size_t)(b * LL + q0);   // base row in mask-class tensors

    // prefetch tile 0's fused mask/adj/dist multiplier (1 reg per row)
    float fm[4];
#pragma unroll
    for (int j = 0; j < 4; ++j) {
        size_t mi = (mrow + wid + 4*j) * LL + kcol;
        int   mk = mask[mi];
        float a  = adj[mi];
        float d  = dist[mi];
        fm[j] = (mk == 1) ? (1.0f + a*wa + d*wd) : 0.0f;
    }

    for (int kt = 0; kt < 32; ++kt) {
        // stage K,V tile (64 x 32)
#pragma unroll
        for (int r = 0; r < 2; ++r) {
            int f   = t + 256 * r;
            int row = f >> 3;
            int c   = (f & 7) << 2;
            float4 kv = *(const float4*)(K + kv_base + (size_t)(kt*64 + row) * DHEAD + c);
            Ks[row][c+0]=kv.x; Ks[row][c+1]=kv.y; Ks[row][c+2]=kv.z; Ks[row][c+3]=kv.w;
            float4 vv = *(const float4*)(V + kv_base + (size_t)(kt*64 + row) * DHEAD + c);
            Vs[row][c+0]=vv.x; Vs[row][c+1]=vv.y; Vs[row][c+2]=vv.z; Vs[row][c+3]=vv.w;
        }
        __syncthreads();

        float4 kf[8];
        {
            const float4* kp = (const float4*)&Ks[kcol][0];
#pragma unroll
            for (int c = 0; c < 8; ++c) kf[c] = kp[c];
        }

        float lv[4];
#pragma unroll
        for (int j = 0; j < 4; ++j) {
            int qq = wid + 4*j;
            float s0 = 0.f;
            const float4* qp = (const float4*)&Qs[qq][0];
#pragma unroll
            for (int c = 0; c < 8; ++c) {
                float4 q4 = qp[c];
                s0 += q4.x*kf[c].x + q4.y*kf[c].y + q4.z*kf[c].z + q4.w*kf[c].w;
            }
            lv[j] = s0 * fm[j] * SCALE_INV;
        }

        // 4 independent max butterflies
        float mloc[4];
#pragma unroll
        for (int j = 0; j < 4; ++j) mloc[j] = lv[j];
#pragma unroll
        for (int off = 1; off < 64; off <<= 1)
#pragma unroll
            for (int j = 0; j < 4; ++j)
                mloc[j] = fmaxf(mloc[j], __shfl_xor(mloc[j], off, 64));

#pragma unroll
        for (int j = 0; j < 4; ++j) {
            int qq = wid + 4*j;
            float mnew  = fmaxf(m[j], mloc[j]);
            float alpha = __expf(m[j] - mnew);
            float p     = __expf(lv[j] - mnew);
            s[j] = s[j]*alpha + p;         // per-lane partial sum
            m[j] = mnew;
            As[qq][kcol] = p;
            if (kcol == 0) As[qq][64] = alpha;
        }
        __syncthreads();

        // prefetch next tile's fused multiplier while PV runs
        if (kt + 1 < 32) {
            const int kgn = (kt+1)*64 + kcol;
#pragma unroll
            for (int j = 0; j < 4; ++j) {
                size_t mi = (mrow + wid + 4*j) * LL + kgn;
                int   mk = mask[mi];
                float a  = adj[mi];
                float d  = dist[mi];
                fm[j] = (mk == 1) ? (1.0f + a*wa + d*wd) : 0.0f;
            }
        }

        // PV: thread (grp,dcol) accumulates rows grp*2..+1, d = dcol
        float sum[2] = {0.f, 0.f};
#pragma unroll
        for (int c = 0; c < 16; ++c) {
            int kl = c * 4;
            float v0 = Vs[kl+0][dcol];
            float v1 = Vs[kl+1][dcol];
            float v2 = Vs[kl+2][dcol];
            float v3 = Vs[kl+3][dcol];
#pragma unroll
            for (int jj = 0; jj < 2; ++jj) {
                float4 a4 = *(const float4*)&As[grp*2+jj][kl];
                sum[jj] += a4.x*v0 + a4.y*v1 + a4.z*v2 + a4.w*v3;
            }
        }
#pragma unroll
        for (int jj = 0; jj < 2; ++jj) {
            int r = grp*2 + jj;
            acc[jj] = acc[jj]*As[r][64] + sum[jj];
        }
        __syncthreads();
    }

    // epilogue: one sum butterfly per row; stats out; ctx scale
#pragma unroll
    for (int j = 0; j < 4; ++j) {
        float ss = s[j];
#pragma unroll
        for (int off = 1; off < 64; off <<= 1)
            ss += __shfl_xor(ss, off, 64);
        float inv = 1.0f / ss;
        int qq = wid + 4*j;
        int qg = q0 + qq;
        if (kcol == 0) {
            As[qq][65] = inv;
            if (bh != 15) { Mall[bh*LL + qg] = m[j]; Sall[bh*LL + qg] = inv; }
            else          { Mw[qg] = m[j];           Sw[qg] = inv; }
        }
    }
    __syncthreads();

#pragma unroll
    for (int jj = 0; jj < 2; ++jj) {
        int r  = grp*2 + jj;
        int qg = q0 + r;
        ctx[(size_t)(bh * LL + qg) * DHEAD + dcol] = acc[jj] * As[r][65];
    }
}

// ---------------- Kernel 3: attn finalize for bh 0..14 — recompute + single write ----
// grid (64, 8, 15). Reads Qw/Kw (L2-resident), M/S stats, recomputes logits,
// writes the final softmax value ONCE.
__global__ __launch_bounds__(256) void attn_final_kernel(
    const float* __restrict__ Q, const float* __restrict__ K,
    const int* __restrict__ mask, const float* __restrict__ adj, const float* __restrict__ dist,
    const float* __restrict__ wA, const float* __restrict__ wD,
    const float* __restrict__ Mall, const float* __restrict__ Sall,
    float* __restrict__ attn)
{
    const int t    = threadIdx.x;
    const int bh   = blockIdx.z;          // 0..14
    const int b    = bh >> 3;
    const int h    = bh & 7;
    const int q0   = blockIdx.x * 32;
    const int kt0  = blockIdx.y * 2;
    const int kcol = t & 63;
    const int wid  = t >> 6;

    __shared__ float Qs[32][36];
    __shared__ float Ks[128][36];

    const float wa = wA[h];
    const float wd = wD[h];

    const size_t qk_base = (size_t)bh * LL * DHEAD;
    float* aout = attn + (size_t)bh * LL2;

    {
        int row = t >> 3;
        int c   = (t & 7) << 2;
        float4 qv = *(const float4*)(Q + qk_base + (size_t)(q0 + row) * DHEAD + c);
        Qs[row][c+0] = qv.x; Qs[row][c+1] = qv.y; Qs[row][c+2] = qv.z; Qs[row][c+3] = qv.w;
    }

    float Mr[8], Sr[8];
#pragma unroll
    for (int j = 0; j < 8; ++j) {
        int qg = q0 + wid + 4*j;
        Mr[j] = Mall[bh*LL + qg];
        Sr[j] = Sall[bh*LL + qg];
    }

    for (int kt = kt0; kt < kt0 + 2; ++kt) {
#pragma unroll
        for (int r = 0; r < 4; ++r) {
            int f   = t + 256 * r;
            int row = f >> 3;
            int c   = (f & 7) << 2;
            float4 kv = *(const float4*)(K + qk_base + (size_t)(kt*128 + row) * DHEAD + c);
            Ks[row][c+0]=kv.x; Ks[row][c+1]=kv.y; Ks[row][c+2]=kv.z; Ks[row][c+3]=kv.w;
        }
        __syncthreads();

        float4 k0[8], k1[8];
        {
            const float4* p0 = (const float4*)&Ks[kcol][0];
            const float4* p1 = (const float4*)&Ks[kcol + 64][0];
#pragma unroll
            for (int c = 0; c < 8; ++c) { k0[c] = p0[c]; k1[c] = p1[c]; }
        }

        const int kg0 = kt*128 + kcol;
#pragma unroll
        for (int j = 0; j < 8; ++j) {
            int qq = wid + 4*j;
            float s0 = 0.f, s1 = 0.f;
            const float4* qp = (const float4*)&Qs[qq][0];
#pragma unroll
            for (int c = 0; c < 8; ++c) {
                float4 q4 = qp[c];
                s0 += q4.x*k0[c].x + q4.y*k0[c].y + q4.z*k0[c].z + q4.w*k0[c].w;
                s1 += q4.x*k1[c].x + q4.y*k1[c].y + q4.z*k1[c].z + q4.w*k1[c].w;
            }
            int qg = q0 + qq;
            size_t mi0 = (size_t)(b * LL + qg) * LL + kg0;
            size_t mi1 = mi0 + 64;
            float fm0 = (mask[mi0] == 1) ? (1.0f + adj[mi0]*wa + dist[mi0]*wd) : 0.0f;
            float fm1 = (mask[mi1] == 1) ? (1.0f + adj[mi1]*wa + dist[mi1]*wd) : 0.0f;
            float l0 = s0 * fm0 * SCALE_INV;
            float l1 = s1 * fm1 * SCALE_INV;
            size_t ai = (size_t)qg * LL + kg0;
            aout[ai]      = __expf(l0 - Mr[j]) * Sr[j];
            aout[ai + 64] = __expf(l1 - Mr[j]) * Sr[j];
        }
        __syncthreads();
    }
}

// ---------------- Kernel 4: output projection ----------------
__global__ __launch_bounds__(256) void out_gemm_kernel(
    const float* __restrict__ ctx, const float* __restrict__ Wo, float* __restrict__ Y)
{
    __shared__ float Xs[64][33];
    __shared__ float Ws[64][33];

    const int t  = threadIdx.x;
    const int m0 = blockIdx.x * 64;
    const int n0 = blockIdx.y * 64;
    const int ty = t >> 4;
    const int tx = t & 15;

    float acc[4][4] = {};

    for (int kt = 0; kt < 8; ++kt) {
#pragma unroll
        for (int r = 0; r < 2; ++r) {
            int f   = t + 256*r;
            int row = f >> 3;
            int c   = (f & 7) << 2;
            int grow = m0 + row;
            int b = grow / LL, l = grow % LL;
            float4 xv4 = *(const float4*)(ctx + (size_t)((b*NH + kt)*LL + l) * DHEAD + c);
            Xs[row][c+0]=xv4.x; Xs[row][c+1]=xv4.y; Xs[row][c+2]=xv4.z; Xs[row][c+3]=xv4.w;
            float4 wv4 = *(const float4*)(Wo + (size_t)(n0 + row) * DMODEL + kt*32 + c);
            Ws[row][c+0]=wv4.x; Ws[row][c+1]=wv4.y; Ws[row][c+2]=wv4.z; Ws[row][c+3]=wv4.w;
        }
        __syncthreads();
#pragma unroll
        for (int kk = 0; kk < 32; ++kk) {
            float a[4], bv[4];
#pragma unroll
            for (int i = 0; i < 4; ++i) a[i]  = Xs[ty*4+i][kk];
#pragma unroll
            for (int j = 0; j < 4; ++j) bv[j] = Ws[tx*4+j][kk];
#pragma unroll
            for (int i = 0; i < 4; ++i)
#pragma unroll
                for (int j = 0; j < 4; ++j)
                    acc[i][j] = fmaf(a[i], bv[j], acc[i][j]);
        }
        __syncthreads();
    }

#pragma unroll
    for (int i = 0; i < 4; ++i) {
        int row = m0 + ty*4 + i;
#pragma unroll
        for (int j = 0; j < 4; ++j) {
            int col = n0 + tx*4 + j;
            Y[(size_t)row * DMODEL + col] = acc[i][j];
        }
    }
}

// ---------------- Kernel 5: attn writes for bh==15, split-k ----------------
// grid (64, 8). Runs LAST (clobbers scratch parked in the bh=15 slab).
__global__ __launch_bounds__(256) void attn15_kernel(
    const float* __restrict__ Q15, const float* __restrict__ K15,
    const int* __restrict__ mask, const float* __restrict__ adj, const float* __restrict__ dist,
    const float* __restrict__ wA, const float* __restrict__ wD,
    const float* __restrict__ Mw, const float* __restrict__ Sw,
    float* __restrict__ attn15)
{
    const int t    = threadIdx.x;
    const int q0   = blockIdx.x * 32;
    const int kt0  = blockIdx.y * 2;
    const int kcol = t & 63;
    const int wid  = t >> 6;

    __shared__ float Qs[32][36];
    __shared__ float Ks[128][36];

    const float wa = wA[7];
    const float wd = wD[7];

    {
        int row = t >> 3;
        int c   = (t & 7) << 2;
        float4 qv = *(const float4*)(Q15 + (size_t)(q0 + row) * DHEAD + c);
        Qs[row][c+0] = qv.x; Qs[row][c+1] = qv.y; Qs[row][c+2] = qv.z; Qs[row][c+3] = qv.w;
    }

    float Mr[8], Sr[8];
#pragma unroll
    for (int j = 0; j < 8; ++j) {
        int qg = q0 + wid + 4*j;
        Mr[j] = Mw[qg];
        Sr[j] = Sw[qg];
    }

    for (int kt = kt0; kt < kt0 + 2; ++kt) {
#pragma unroll
        for (int r = 0; r < 4; ++r) {
            int f   = t + 256 * r;
            int row = f >> 3;
            int c   = (f & 7) << 2;
            float4 kv = *(const float4*)(K15 + (size_t)(kt*128 + row) * DHEAD + c);
            Ks[row][c+0]=kv.x; Ks[row][c+1]=kv.y; Ks[row][c+2]=kv.z; Ks[row][c+3]=kv.w;
        }
        __syncthreads();

        float4 k0[8], k1[8];
        {
            const float4* p0 = (const float4*)&Ks[kcol][0];
            const float4* p1 = (const float4*)&Ks[kcol + 64][0];
#pragma unroll
            for (int c = 0; c < 8; ++c) { k0[c] = p0[c]; k1[c] = p1[c]; }
        }

        const int kg0 = kt*128 + kcol;
#pragma unroll
        for (int j = 0; j < 8; ++j) {
            int qq = wid + 4*j;
            float s0 = 0.f, s1 = 0.f;
            const float4* qp = (const float4*)&Qs[qq][0];
#pragma unroll
            for (int c = 0; c < 8; ++c) {
                float4 q4 = qp[c];
                s0 += q4.x*k0[c].x + q4.y*k0[c].y + q4.z*k0[c].z + q4.w*k0[c].w;
                s1 += q4.x*k1[c].x + q4.y*k1[c].y + q4.z*k1[c].z + q4.w*k1[c].w;
            }
            int qg = q0 + qq;
            size_t mi0 = (size_t)(LL + qg) * LL + kg0;      // b = 1
            size_t mi1 = mi0 + 64;
            float sm0 = (mask[mi0] == 1) ? s0 : 0.0f;
            float sm1 = (mask[mi1] == 1) ? s1 : 0.0f;
            float l0 = sm0 * (1.0f + adj[mi0]*wa + dist[mi0]*wd) * SCALE_INV;
            float l1 = sm1 * (1.0f + adj[mi1]*wa + dist[mi1]*wd) * SCALE_INV;
            size_t ai = (size_t)qg * LL + kg0;
            attn15[ai]      = __expf(l0 - Mr[j]) * Sr[j];
            attn15[ai + 64] = __expf(l1 - Mr[j]) * Sr[j];
        }
        __syncthreads();
    }
}

extern "C" void kernel_launch(void* const* d_in, const int* in_sizes, int n_in,
                              void* d_out, int out_size, void* d_ws, size_t ws_size,
                              hipStream_t stream)
{
    const float* q    = (const float*)d_in[0];
    const float* k    = (const float*)d_in[1];
    const float* v    = (const float*)d_in[2];
    const int*   mask = (const int*)d_in[3];
    const float* adj  = (const float*)d_in[4];
    const float* dist = (const float*)d_in[5];
    const float* Wq   = (const float*)d_in[6];
    const float* Wk   = (const float*)d_in[7];
    const float* Wv   = (const float*)d_in[8];
    const float* Wo   = (const float*)d_in[9];
    const float* wA   = (const float*)d_in[10];
    const float* wD   = (const float*)d_in[11];

    float* out  = (float*)d_out;                       // B*L*DM = 1,048,576 floats
    float* attn = out + (size_t)BB*LL*DMODEL;          // B*H*L*L

    // Scratch parked in attn[bh=15]'s slab (4*NQ floats = 16 MB, dead until attn15).
    float* tail = attn + (size_t)15 * LL2;
    float* Qw = tail;
    float* Kw = tail + (size_t)NQ;
    float* Vw = tail + (size_t)2 * NQ;
    float* Cw = tail + (size_t)3 * NQ;

    // Softmax stats (bh<15) parked in `out` (dead until out_gemm; attn_final
    // consumes them BEFORE out_gemm runs).
    float* Mall = out;                 // 15*2048 floats
    float* Sall = out + 32768;         // 15*2048 floats

    // Tiny ws: bh=15 Q/K slices + bh=15 stats (528 KB).
    float* Q15 = (float*)d_ws;
    float* K15 = Q15 + (size_t)LL * DHEAD;
    float* Mw  = K15 + (size_t)LL * DHEAD;
    float* Sw  = Mw + LL;

    dim3 g1(64, 4, 3);
    proj_kernel<<<g1, 256, 0, stream>>>(q, k, v, Wq, Wk, Wv, Qw, Kw, Vw, Q15, K15);

    dim3 g2(LL/16, BB*NH);
    attn_main_kernel<<<g2, 256, 0, stream>>>(Qw, Kw, Vw, mask, adj, dist, wA, wD,
                                             Cw, Mall, Sall, Mw, Sw);

    // bh<15 attn: recompute + single write (reads Qw/Kw + Mall/Sall in `out`)
    dim3 gf(64, 8, 15);
    attn_final_kernel<<<gf, 256, 0, stream>>>(Qw, Kw, mask, adj, dist, wA, wD,
                                              Mall, Sall, attn);

    // out projection (overwrites `out`, consumes Cw)
    dim3 g3(64, 4);
    out_gemm_kernel<<<g3, 256, 0, stream>>>(Cw, Wo, out);

    // bh=15 attn last (clobbers scratch slab; reads ws duplicates)
    dim3 g4(64, 8);
    attn15_kernel<<<g4, 256, 0, stream>>>(Q15, K15, mask, adj, dist, wA, wD, Mw, Sw,
                                          attn + (size_t)15 * LL2);
}

// Round 6
// 1170.544 us; speedup vs baseline: 1.0783x; 1.0697x over previous
//
#include <hip/hip_runtime.h>
#include <math.h>

#define BB 2
#define LL 2048
#define DMODEL 256
#define NH 8
#define DHEAD 32
#define LL2 (LL*LL)            // 4,194,304 floats per (b,h) attn slab
#define NQ (BB*NH*LL*DHEAD)    // 1,048,576 floats per Q/K/V/ctx tensor

constexpr float SCALE_INV = 0.17677669529663687f;  // 1/sqrt(32)

// ---------------- Kernel 1: QKV projections ----------------
__global__ __launch_bounds__(256) void proj_kernel(
    const float* __restrict__ xq, const float* __restrict__ xk, const float* __restrict__ xv,
    const float* __restrict__ Wq, const float* __restrict__ Wk, const float* __restrict__ Wv,
    float* __restrict__ Qo, float* __restrict__ Ko, float* __restrict__ Vo,
    float* __restrict__ Q15, float* __restrict__ K15)
{
    const float* X; const float* W; float* O; float* dup;
    if (blockIdx.z == 0)      { X = xq; W = Wq; O = Qo; dup = Q15; }
    else if (blockIdx.z == 1) { X = xk; W = Wk; O = Ko; dup = K15; }
    else                      { X = xv; W = Wv; O = Vo; dup = nullptr; }

    __shared__ float Xs[64][33];
    __shared__ float Ws[64][33];

    const int t  = threadIdx.x;
    const int m0 = blockIdx.x * 64;
    const int n0 = blockIdx.y * 64;
    const int ty = t >> 4;
    const int tx = t & 15;

    float acc[4][4] = {};

    for (int k0 = 0; k0 < DMODEL; k0 += 32) {
#pragma unroll
        for (int r = 0; r < 2; ++r) {
            int f   = t + 256 * r;
            int row = f >> 3;
            int c   = (f & 7) << 2;
            float4 xv4 = *(const float4*)(X + (size_t)(m0 + row) * DMODEL + k0 + c);
            Xs[row][c+0] = xv4.x; Xs[row][c+1] = xv4.y; Xs[row][c+2] = xv4.z; Xs[row][c+3] = xv4.w;
            float4 wv4 = *(const float4*)(W + (size_t)(n0 + row) * DMODEL + k0 + c);
            Ws[row][c+0] = wv4.x; Ws[row][c+1] = wv4.y; Ws[row][c+2] = wv4.z; Ws[row][c+3] = wv4.w;
        }
        __syncthreads();
#pragma unroll
        for (int kk = 0; kk < 32; ++kk) {
            float a[4], bv[4];
#pragma unroll
            for (int i = 0; i < 4; ++i) a[i]  = Xs[ty*4+i][kk];
#pragma unroll
            for (int j = 0; j < 4; ++j) bv[j] = Ws[tx*4+j][kk];
#pragma unroll
            for (int i = 0; i < 4; ++i)
#pragma unroll
                for (int j = 0; j < 4; ++j)
                    acc[i][j] = fmaf(a[i], bv[j], acc[i][j]);
        }
        __syncthreads();
    }

#pragma unroll
    for (int i = 0; i < 4; ++i) {
        int row = m0 + ty*4 + i;
        int b   = row / LL;
        int l   = row % LL;
#pragma unroll
        for (int j = 0; j < 4; ++j) {
            int col = n0 + tx*4 + j;
            int h   = col >> 5;
            int d   = col & 31;
            O[(size_t)(((b*NH + h)*LL) + l) * DHEAD + d] = acc[i][j];
            if (dup && row >= LL && col >= 224) {
                dup[(size_t)(row - LL) * DHEAD + (col - 224)] = acc[i][j];
            }
        }
    }
}

// ---------------- Kernel 2: pure flash pass (NO attn store) ----------------
// v7: QBLK=16 kept (R5: occupancy 25->51%). launch_bounds 6 -> 4: empirically
// the allocator budget is ~256/arg2 VGPRs (R0:64@4, R4:80@3, R5:40@6). arg=6
// capped at 40 < the ~56 needed -> 19 B/thread/tile spill = 330 MB WRITE_SIZE,
// which ate the occupancy win. arg=4 caps at 64: no spill, 4 blocks/CU by
// VGPR (LDS would allow 6). Tripwire: WRITE_SIZE must return to ~4.5 MB.
__global__ __launch_bounds__(256, 4) void attn_main_kernel(
    const float* __restrict__ Q, const float* __restrict__ K, const float* __restrict__ V,
    const int* __restrict__ mask, const float* __restrict__ adj, const float* __restrict__ dist,
    const float* __restrict__ wA, const float* __restrict__ wD,
    float* __restrict__ ctx,
    float* __restrict__ Mall, float* __restrict__ Sall,
    float* __restrict__ Mw, float* __restrict__ Sw)
{
    const int t    = threadIdx.x;
    const int bh   = blockIdx.y;
    const int b    = bh >> 3;
    const int h    = bh & 7;
    const int q0   = blockIdx.x * 16;
    const int kcol = t & 63;
    const int wid  = t >> 6;          // 0..3
    const int dcol = t & 31;
    const int grp  = t >> 5;          // 0..7

    __shared__ float Qs[16][36];
    __shared__ float Ks[64][36];
    __shared__ float Vs[64][36];
    __shared__ float As[16][68];   // 0..63 = p; 64 = alpha; 65 = invS

    const float wa = wA[h];
    const float wd = wD[h];

    if (t < 128) {   // Q tile 16x32
        int row = t >> 3;
        int c   = (t & 7) << 2;
        float4 qv = *(const float4*)(Q + (size_t)(bh * LL + q0 + row) * DHEAD + c);
        Qs[row][c+0] = qv.x; Qs[row][c+1] = qv.y; Qs[row][c+2] = qv.z; Qs[row][c+3] = qv.w;
    }

    float m[4], s[4];
#pragma unroll
    for (int j = 0; j < 4; ++j) { m[j] = -INFINITY; s[j] = 0.0f; }
    float acc[2] = {0.f, 0.f};

    const size_t kv_base = (size_t)bh * LL * DHEAD;
    const size_t mrow    = (size_t)(b * LL + q0);   // base row in mask-class tensors

    // prefetch tile 0's fused mask/adj/dist multiplier (1 reg per row)
    float fm[4];
#pragma unroll
    for (int j = 0; j < 4; ++j) {
        size_t mi = (mrow + wid + 4*j) * LL + kcol;
        int   mk = mask[mi];
        float a  = adj[mi];
        float d  = dist[mi];
        fm[j] = (mk == 1) ? (1.0f + a*wa + d*wd) : 0.0f;
    }

    for (int kt = 0; kt < 32; ++kt) {
        // stage K,V tile (64 x 32)
#pragma unroll
        for (int r = 0; r < 2; ++r) {
            int f   = t + 256 * r;
            int row = f >> 3;
            int c   = (f & 7) << 2;
            float4 kv = *(const float4*)(K + kv_base + (size_t)(kt*64 + row) * DHEAD + c);
            Ks[row][c+0]=kv.x; Ks[row][c+1]=kv.y; Ks[row][c+2]=kv.z; Ks[row][c+3]=kv.w;
            float4 vv = *(const float4*)(V + kv_base + (size_t)(kt*64 + row) * DHEAD + c);
            Vs[row][c+0]=vv.x; Vs[row][c+1]=vv.y; Vs[row][c+2]=vv.z; Vs[row][c+3]=vv.w;
        }
        __syncthreads();

        float4 kf[8];
        {
            const float4* kp = (const float4*)&Ks[kcol][0];
#pragma unroll
            for (int c = 0; c < 8; ++c) kf[c] = kp[c];
        }

        float lv[4];
#pragma unroll
        for (int j = 0; j < 4; ++j) {
            int qq = wid + 4*j;
            float s0 = 0.f;
            const float4* qp = (const float4*)&Qs[qq][0];
#pragma unroll
            for (int c = 0; c < 8; ++c) {
                float4 q4 = qp[c];
                s0 += q4.x*kf[c].x + q4.y*kf[c].y + q4.z*kf[c].z + q4.w*kf[c].w;
            }
            lv[j] = s0 * fm[j] * SCALE_INV;
        }

        // 4 independent max butterflies
        float mloc[4];
#pragma unroll
        for (int j = 0; j < 4; ++j) mloc[j] = lv[j];
#pragma unroll
        for (int off = 1; off < 64; off <<= 1)
#pragma unroll
            for (int j = 0; j < 4; ++j)
                mloc[j] = fmaxf(mloc[j], __shfl_xor(mloc[j], off, 64));

#pragma unroll
        for (int j = 0; j < 4; ++j) {
            int qq = wid + 4*j;
            float mnew  = fmaxf(m[j], mloc[j]);
            float alpha = __expf(m[j] - mnew);
            float p     = __expf(lv[j] - mnew);
            s[j] = s[j]*alpha + p;         // per-lane partial sum
            m[j] = mnew;
            As[qq][kcol] = p;
            if (kcol == 0) As[qq][64] = alpha;
        }
        __syncthreads();

        // prefetch next tile's fused multiplier while PV runs
        if (kt + 1 < 32) {
            const int kgn = (kt+1)*64 + kcol;
#pragma unroll
            for (int j = 0; j < 4; ++j) {
                size_t mi = (mrow + wid + 4*j) * LL + kgn;
                int   mk = mask[mi];
                float a  = adj[mi];
                float d  = dist[mi];
                fm[j] = (mk == 1) ? (1.0f + a*wa + d*wd) : 0.0f;
            }
        }

        // PV: thread (grp,dcol) accumulates rows grp*2..+1, d = dcol
        float sum[2] = {0.f, 0.f};
#pragma unroll
        for (int c = 0; c < 16; ++c) {
            int kl = c * 4;
            float v0 = Vs[kl+0][dcol];
            float v1 = Vs[kl+1][dcol];
            float v2 = Vs[kl+2][dcol];
            float v3 = Vs[kl+3][dcol];
#pragma unroll
            for (int jj = 0; jj < 2; ++jj) {
                float4 a4 = *(const float4*)&As[grp*2+jj][kl];
                sum[jj] += a4.x*v0 + a4.y*v1 + a4.z*v2 + a4.w*v3;
            }
        }
#pragma unroll
        for (int jj = 0; jj < 2; ++jj) {
            int r = grp*2 + jj;
            acc[jj] = acc[jj]*As[r][64] + sum[jj];
        }
        __syncthreads();
    }

    // epilogue: one sum butterfly per row; stats out; ctx scale
#pragma unroll
    for (int j = 0; j < 4; ++j) {
        float ss = s[j];
#pragma unroll
        for (int off = 1; off < 64; off <<= 1)
            ss += __shfl_xor(ss, off, 64);
        float inv = 1.0f / ss;
        int qq = wid + 4*j;
        int qg = q0 + qq;
        if (kcol == 0) {
            As[qq][65] = inv;
            if (bh != 15) { Mall[bh*LL + qg] = m[j]; Sall[bh*LL + qg] = inv; }
            else          { Mw[qg] = m[j];           Sw[qg] = inv; }
        }
    }
    __syncthreads();

#pragma unroll
    for (int jj = 0; jj < 2; ++jj) {
        int r  = grp*2 + jj;
        int qg = q0 + r;
        ctx[(size_t)(bh * LL + qg) * DHEAD + dcol] = acc[jj] * As[r][65];
    }
}

// ---------------- Kernel 3: attn finalize for bh 0..14 — recompute + single write ----
// grid (64, 8, 15). Reads Qw/Kw (L2-resident), M/S stats, recomputes logits,
// writes the final softmax value ONCE.
__global__ __launch_bounds__(256) void attn_final_kernel(
    const float* __restrict__ Q, const float* __restrict__ K,
    const int* __restrict__ mask, const float* __restrict__ adj, const float* __restrict__ dist,
    const float* __restrict__ wA, const float* __restrict__ wD,
    const float* __restrict__ Mall, const float* __restrict__ Sall,
    float* __restrict__ attn)
{
    const int t    = threadIdx.x;
    const int bh   = blockIdx.z;          // 0..14
    const int b    = bh >> 3;
    const int h    = bh & 7;
    const int q0   = blockIdx.x * 32;
    const int kt0  = blockIdx.y * 2;
    const int kcol = t & 63;
    const int wid  = t >> 6;

    __shared__ float Qs[32][36];
    __shared__ float Ks[128][36];

    const float wa = wA[h];
    const float wd = wD[h];

    const size_t qk_base = (size_t)bh * LL * DHEAD;
    float* aout = attn + (size_t)bh * LL2;

    {
        int row = t >> 3;
        int c   = (t & 7) << 2;
        float4 qv = *(const float4*)(Q + qk_base + (size_t)(q0 + row) * DHEAD + c);
        Qs[row][c+0] = qv.x; Qs[row][c+1] = qv.y; Qs[row][c+2] = qv.z; Qs[row][c+3] = qv.w;
    }

    float Mr[8], Sr[8];
#pragma unroll
    for (int j = 0; j < 8; ++j) {
        int qg = q0 + wid + 4*j;
        Mr[j] = Mall[bh*LL + qg];
        Sr[j] = Sall[bh*LL + qg];
    }

    for (int kt = kt0; kt < kt0 + 2; ++kt) {
#pragma unroll
        for (int r = 0; r < 4; ++r) {
            int f   = t + 256 * r;
            int row = f >> 3;
            int c   = (f & 7) << 2;
            float4 kv = *(const float4*)(K + qk_base + (size_t)(kt*128 + row) * DHEAD + c);
            Ks[row][c+0]=kv.x; Ks[row][c+1]=kv.y; Ks[row][c+2]=kv.z; Ks[row][c+3]=kv.w;
        }
        __syncthreads();

        float4 k0[8], k1[8];
        {
            const float4* p0 = (const float4*)&Ks[kcol][0];
            const float4* p1 = (const float4*)&Ks[kcol + 64][0];
#pragma unroll
            for (int c = 0; c < 8; ++c) { k0[c] = p0[c]; k1[c] = p1[c]; }
        }

        const int kg0 = kt*128 + kcol;
#pragma unroll
        for (int j = 0; j < 8; ++j) {
            int qq = wid + 4*j;
            float s0 = 0.f, s1 = 0.f;
            const float4* qp = (const float4*)&Qs[qq][0];
#pragma unroll
            for (int c = 0; c < 8; ++c) {
                float4 q4 = qp[c];
                s0 += q4.x*k0[c].x + q4.y*k0[c].y + q4.z*k0[c].z + q4.w*k0[c].w;
                s1 += q4.x*k1[c].x + q4.y*k1[c].y + q4.z*k1[c].z + q4.w*k1[c].w;
            }
            int qg = q0 + qq;
            size_t mi0 = (size_t)(b * LL + qg) * LL + kg0;
            size_t mi1 = mi0 + 64;
            float fm0 = (mask[mi0] == 1) ? (1.0f + adj[mi0]*wa + dist[mi0]*wd) : 0.0f;
            float fm1 = (mask[mi1] == 1) ? (1.0f + adj[mi1]*wa + dist[mi1]*wd) : 0.0f;
            float l0 = s0 * fm0 * SCALE_INV;
            float l1 = s1 * fm1 * SCALE_INV;
            size_t ai = (size_t)qg * LL + kg0;
            aout[ai]      = __expf(l0 - Mr[j]) * Sr[j];
            aout[ai + 64] = __expf(l1 - Mr[j]) * Sr[j];
        }
        __syncthreads();
    }
}

// ---------------- Kernel 4: output projection ----------------
__global__ __launch_bounds__(256) void out_gemm_kernel(
    const float* __restrict__ ctx, const float* __restrict__ Wo, float* __restrict__ Y)
{
    __shared__ float Xs[64][33];
    __shared__ float Ws[64][33];

    const int t  = threadIdx.x;
    const int m0 = blockIdx.x * 64;
    const int n0 = blockIdx.y * 64;
    const int ty = t >> 4;
    const int tx = t & 15;

    float acc[4][4] = {};

    for (int kt = 0; kt < 8; ++kt) {
#pragma unroll
        for (int r = 0; r < 2; ++r) {
            int f   = t + 256*r;
            int row = f >> 3;
            int c   = (f & 7) << 2;
            int grow = m0 + row;
            int b = grow / LL, l = grow % LL;
            float4 xv4 = *(const float4*)(ctx + (size_t)((b*NH + kt)*LL + l) * DHEAD + c);
            Xs[row][c+0]=xv4.x; Xs[row][c+1]=xv4.y; Xs[row][c+2]=xv4.z; Xs[row][c+3]=xv4.w;
            float4 wv4 = *(const float4*)(Wo + (size_t)(n0 + row) * DMODEL + kt*32 + c);
            Ws[row][c+0]=wv4.x; Ws[row][c+1]=wv4.y; Ws[row][c+2]=wv4.z; Ws[row][c+3]=wv4.w;
        }
        __syncthreads();
#pragma unroll
        for (int kk = 0; kk < 32; ++kk) {
            float a[4], bv[4];
#pragma unroll
            for (int i = 0; i < 4; ++i) a[i]  = Xs[ty*4+i][kk];
#pragma unroll
            for (int j = 0; j < 4; ++j) bv[j] = Ws[tx*4+j][kk];
#pragma unroll
            for (int i = 0; i < 4; ++i)
#pragma unroll
                for (int j = 0; j < 4; ++j)
                    acc[i][j] = fmaf(a[i], bv[j], acc[i][j]);
        }
        __syncthreads();
    }

#pragma unroll
    for (int i = 0; i < 4; ++i) {
        int row = m0 + ty*4 + i;
#pragma unroll
        for (int j = 0; j < 4; ++j) {
            int col = n0 + tx*4 + j;
            Y[(size_t)row * DMODEL + col] = acc[i][j];
        }
    }
}

// ---------------- Kernel 5: attn writes for bh==15, split-k ----------------
// grid (64, 8). Runs LAST (clobbers scratch parked in the bh=15 slab).
__global__ __launch_bounds__(256) void attn15_kernel(
    const float* __restrict__ Q15, const float* __restrict__ K15,
    const int* __restrict__ mask, const float* __restrict__ adj, const float* __restrict__ dist,
    const float* __restrict__ wA, const float* __restrict__ wD,
    const float* __restrict__ Mw, const float* __restrict__ Sw,
    float* __restrict__ attn15)
{
    const int t    = threadIdx.x;
    const int q0   = blockIdx.x * 32;
    const int kt0  = blockIdx.y * 2;
    const int kcol = t & 63;
    const int wid  = t >> 6;

    __shared__ float Qs[32][36];
    __shared__ float Ks[128][36];

    const float wa = wA[7];
    const float wd = wD[7];

    {
        int row = t >> 3;
        int c   = (t & 7) << 2;
        float4 qv = *(const float4*)(Q15 + (size_t)(q0 + row) * DHEAD + c);
        Qs[row][c+0] = qv.x; Qs[row][c+1] = qv.y; Qs[row][c+2] = qv.z; Qs[row][c+3] = qv.w;
    }

    float Mr[8], Sr[8];
#pragma unroll
    for (int j = 0; j < 8; ++j) {
        int qg = q0 + wid + 4*j;
        Mr[j] = Mw[qg];
        Sr[j] = Sw[qg];
    }

    for (int kt = kt0; kt < kt0 + 2; ++kt) {
#pragma unroll
        for (int r = 0; r < 4; ++r) {
            int f   = t + 256 * r;
            int row = f >> 3;
            int c   = (f & 7) << 2;
            float4 kv = *(const float4*)(K15 + (size_t)(kt*128 + row) * DHEAD + c);
            Ks[row][c+0]=kv.x; Ks[row][c+1]=kv.y; Ks[row][c+2]=kv.z; Ks[row][c+3]=kv.w;
        }
        __syncthreads();

        float4 k0[8], k1[8];
        {
            const float4* p0 = (const float4*)&Ks[kcol][0];
            const float4* p1 = (const float4*)&Ks[kcol + 64][0];
#pragma unroll
            for (int c = 0; c < 8; ++c) { k0[c] = p0[c]; k1[c] = p1[c]; }
        }

        const int kg0 = kt*128 + kcol;
#pragma unroll
        for (int j = 0; j < 8; ++j) {
            int qq = wid + 4*j;
            float s0 = 0.f, s1 = 0.f;
            const float4* qp = (const float4*)&Qs[qq][0];
#pragma unroll
            for (int c = 0; c < 8; ++c) {
                float4 q4 = qp[c];
                s0 += q4.x*k0[c].x + q4.y*k0[c].y + q4.z*k0[c].z + q4.w*k0[c].w;
                s1 += q4.x*k1[c].x + q4.y*k1[c].y + q4.z*k1[c].z + q4.w*k1[c].w;
            }
            int qg = q0 + qq;
            size_t mi0 = (size_t)(LL + qg) * LL + kg0;      // b = 1
            size_t mi1 = mi0 + 64;
            float sm0 = (mask[mi0] == 1) ? s0 : 0.0f;
            float sm1 = (mask[mi1] == 1) ? s1 : 0.0f;
            float l0 = sm0 * (1.0f + adj[mi0]*wa + dist[mi0]*wd) * SCALE_INV;
            float l1 = sm1 * (1.0f + adj[mi1]*wa + dist[mi1]*wd) * SCALE_INV;
            size_t ai = (size_t)qg * LL + kg0;
            attn15[ai]      = __expf(l0 - Mr[j]) * Sr[j];
            attn15[ai + 64] = __expf(l1 - Mr[j]) * Sr[j];
        }
        __syncthreads();
    }
}

extern "C" void kernel_launch(void* const* d_in, const int* in_sizes, int n_in,
                              void* d_out, int out_size, void* d_ws, size_t ws_size,
                              hipStream_t stream)
{
    const float* q    = (const float*)d_in[0];
    const float* k    = (const float*)d_in[1];
    const float* v    = (const float*)d_in[2];
    const int*   mask = (const int*)d_in[3];
    const float* adj  = (const float*)d_in[4];
    const float* dist = (const float*)d_in[5];
    const float* Wq   = (const float*)d_in[6];
    const float* Wk   = (const float*)d_in[7];
    const float* Wv   = (const float*)d_in[8];
    const float* Wo   = (const float*)d_in[9];
    const float* wA   = (const float*)d_in[10];
    const float* wD   = (const float*)d_in[11];

    float* out  = (float*)d_out;                       // B*L*DM = 1,048,576 floats
    float* attn = out + (size_t)BB*LL*DMODEL;          // B*H*L*L

    // Scratch parked in attn[bh=15]'s slab (4*NQ floats = 16 MB, dead until attn15).
    float* tail = attn + (size_t)15 * LL2;
    float* Qw = tail;
    float* Kw = tail + (size_t)NQ;
    float* Vw = tail + (size_t)2 * NQ;
    float* Cw = tail + (size_t)3 * NQ;

    // Softmax stats (bh<15) parked in `out` (dead until out_gemm; attn_final
    // consumes them BEFORE out_gemm runs).
    float* Mall = out;                 // 15*2048 floats
    float* Sall = out + 32768;         // 15*2048 floats

    // Tiny ws: bh=15 Q/K slices + bh=15 stats (528 KB).
    float* Q15 = (float*)d_ws;
    float* K15 = Q15 + (size_t)LL * DHEAD;
    float* Mw  = K15 + (size_t)LL * DHEAD;
    float* Sw  = Mw + LL;

    dim3 g1(64, 4, 3);
    proj_kernel<<<g1, 256, 0, stream>>>(q, k, v, Wq, Wk, Wv, Qw, Kw, Vw, Q15, K15);

    dim3 g2(LL/16, BB*NH);
    attn_main_kernel<<<g2, 256, 0, stream>>>(Qw, Kw, Vw, mask, adj, dist, wA, wD,
                                             Cw, Mall, Sall, Mw, Sw);

    // bh<15 attn: recompute + single write (reads Qw/Kw + Mall/Sall in `out`)
    dim3 gf(64, 8, 15);
    attn_final_kernel<<<gf, 256, 0, stream>>>(Qw, Kw, mask, adj, dist, wA, wD,
                                              Mall, Sall, attn);

    // out projection (overwrites `out`, consumes Cw)
    dim3 g3(64, 4);
    out_gemm_kernel<<<g3, 256, 0, stream>>>(Cw, Wo, out);

    // bh=15 attn last (clobbers scratch slab; reads ws duplicates)
    dim3 g4(64, 8);
    attn15_kernel<<<g4, 256, 0, stream>>>(Q15, K15, mask, adj, dist, wA, wD, Mw, Sw,
                                          attn + (size_t)15 * LL2);
}

// Round 7
// 1167.884 us; speedup vs baseline: 1.0808x; 1.0023x over previous
//
#include <hip/hip_runtime.h>
#include <math.h>

#define BB 2
#define LL 2048
#define DMODEL 256
#define NH 8
#define DHEAD 32
#define LL2 (LL*LL)            // 4,194,304 floats per (b,h) attn slab
#define NQ (BB*NH*LL*DHEAD)    // 1,048,576 floats per Q/K/V/ctx tensor

constexpr float SCALE_INV = 0.17677669529663687f;  // 1/sqrt(32)

// ---------------- Kernel 1: QKV projections ----------------
__global__ __launch_bounds__(256) void proj_kernel(
    const float* __restrict__ xq, const float* __restrict__ xk, const float* __restrict__ xv,
    const float* __restrict__ Wq, const float* __restrict__ Wk, const float* __restrict__ Wv,
    float* __restrict__ Qo, float* __restrict__ Ko, float* __restrict__ Vo,
    float* __restrict__ Q15, float* __restrict__ K15)
{
    const float* X; const float* W; float* O; float* dup;
    if (blockIdx.z == 0)      { X = xq; W = Wq; O = Qo; dup = Q15; }
    else if (blockIdx.z == 1) { X = xk; W = Wk; O = Ko; dup = K15; }
    else                      { X = xv; W = Wv; O = Vo; dup = nullptr; }

    __shared__ float Xs[64][33];
    __shared__ float Ws[64][33];

    const int t  = threadIdx.x;
    const int m0 = blockIdx.x * 64;
    const int n0 = blockIdx.y * 64;
    const int ty = t >> 4;
    const int tx = t & 15;

    float acc[4][4] = {};

    for (int k0 = 0; k0 < DMODEL; k0 += 32) {
#pragma unroll
        for (int r = 0; r < 2; ++r) {
            int f   = t + 256 * r;
            int row = f >> 3;
            int c   = (f & 7) << 2;
            float4 xv4 = *(const float4*)(X + (size_t)(m0 + row) * DMODEL + k0 + c);
            Xs[row][c+0] = xv4.x; Xs[row][c+1] = xv4.y; Xs[row][c+2] = xv4.z; Xs[row][c+3] = xv4.w;
            float4 wv4 = *(const float4*)(W + (size_t)(n0 + row) * DMODEL + k0 + c);
            Ws[row][c+0] = wv4.x; Ws[row][c+1] = wv4.y; Ws[row][c+2] = wv4.z; Ws[row][c+3] = wv4.w;
        }
        __syncthreads();
#pragma unroll
        for (int kk = 0; kk < 32; ++kk) {
            float a[4], bv[4];
#pragma unroll
            for (int i = 0; i < 4; ++i) a[i]  = Xs[ty*4+i][kk];
#pragma unroll
            for (int j = 0; j < 4; ++j) bv[j] = Ws[tx*4+j][kk];
#pragma unroll
            for (int i = 0; i < 4; ++i)
#pragma unroll
                for (int j = 0; j < 4; ++j)
                    acc[i][j] = fmaf(a[i], bv[j], acc[i][j]);
        }
        __syncthreads();
    }

#pragma unroll
    for (int i = 0; i < 4; ++i) {
        int row = m0 + ty*4 + i;
        int b   = row / LL;
        int l   = row % LL;
#pragma unroll
        for (int j = 0; j < 4; ++j) {
            int col = n0 + tx*4 + j;
            int h   = col >> 5;
            int d   = col & 31;
            O[(size_t)(((b*NH + h)*LL) + l) * DHEAD + d] = acc[i][j];
            if (dup && row >= LL && col >= 224) {
                dup[(size_t)(row - LL) * DHEAD + (col - 224)] = acc[i][j];
            }
        }
    }
}

// ---------------- Kernel 2: pure flash pass (NO attn store) ----------------
// v8: two-phase QK dot. R6 still spilled 3 dwords/thread/tile (WRITE_SIZE
// 207 MB vs 4.5 ideal): peak pressure ~67 regs > the 64 cap, dominated by
// kf[8] = 32 VGPRs of K-fragment held across the whole dot. Split the dot
// over D: load kf[4] (cols 0..15), partial-accumulate lv[], REUSE the same
// 4 regs for cols 16..31. Peak K-frag pressure 32 -> 16. sched_barrier(0)
// between halves stops the scheduler re-fusing the live ranges.
// Tripwire: WRITE_SIZE must drop to ~4.5 MB.
__global__ __launch_bounds__(256, 4) void attn_main_kernel(
    const float* __restrict__ Q, const float* __restrict__ K, const float* __restrict__ V,
    const int* __restrict__ mask, const float* __restrict__ adj, const float* __restrict__ dist,
    const float* __restrict__ wA, const float* __restrict__ wD,
    float* __restrict__ ctx,
    float* __restrict__ Mall, float* __restrict__ Sall,
    float* __restrict__ Mw, float* __restrict__ Sw)
{
    const int t    = threadIdx.x;
    const int bh   = blockIdx.y;
    const int b    = bh >> 3;
    const int h    = bh & 7;
    const int q0   = blockIdx.x * 16;
    const int kcol = t & 63;
    const int wid  = t >> 6;          // 0..3
    const int dcol = t & 31;
    const int grp  = t >> 5;          // 0..7

    __shared__ float Qs[16][36];
    __shared__ float Ks[64][36];
    __shared__ float Vs[64][36];
    __shared__ float As[16][68];   // 0..63 = p; 64 = alpha; 65 = invS

    const float wa = wA[h];
    const float wd = wD[h];

    if (t < 128) {   // Q tile 16x32
        int row = t >> 3;
        int c   = (t & 7) << 2;
        float4 qv = *(const float4*)(Q + (size_t)(bh * LL + q0 + row) * DHEAD + c);
        Qs[row][c+0] = qv.x; Qs[row][c+1] = qv.y; Qs[row][c+2] = qv.z; Qs[row][c+3] = qv.w;
    }

    float m[4], s[4];
#pragma unroll
    for (int j = 0; j < 4; ++j) { m[j] = -INFINITY; s[j] = 0.0f; }
    float acc[2] = {0.f, 0.f};

    const size_t kv_base = (size_t)bh * LL * DHEAD;
    const size_t mrow    = (size_t)(b * LL + q0);   // base row in mask-class tensors

    // prefetch tile 0's fused mask/adj/dist multiplier (1 reg per row)
    float fm[4];
#pragma unroll
    for (int j = 0; j < 4; ++j) {
        size_t mi = (mrow + wid + 4*j) * LL + kcol;
        int   mk = mask[mi];
        float a  = adj[mi];
        float d  = dist[mi];
        fm[j] = (mk == 1) ? (1.0f + a*wa + d*wd) : 0.0f;
    }

    for (int kt = 0; kt < 32; ++kt) {
        // stage K,V tile (64 x 32)
#pragma unroll
        for (int r = 0; r < 2; ++r) {
            int f   = t + 256 * r;
            int row = f >> 3;
            int c   = (f & 7) << 2;
            float4 kv = *(const float4*)(K + kv_base + (size_t)(kt*64 + row) * DHEAD + c);
            Ks[row][c+0]=kv.x; Ks[row][c+1]=kv.y; Ks[row][c+2]=kv.z; Ks[row][c+3]=kv.w;
            float4 vv = *(const float4*)(V + kv_base + (size_t)(kt*64 + row) * DHEAD + c);
            Vs[row][c+0]=vv.x; Vs[row][c+1]=vv.y; Vs[row][c+2]=vv.z; Vs[row][c+3]=vv.w;
        }
        __syncthreads();

        // two-phase QK dot: only 4 K-fragment float4s live at a time
        float lv[4] = {0.f, 0.f, 0.f, 0.f};
#pragma unroll
        for (int half = 0; half < 2; ++half) {
            float4 kf[4];
            {
                const float4* kp = (const float4*)&Ks[kcol][0];
#pragma unroll
                for (int c = 0; c < 4; ++c) kf[c] = kp[half*4 + c];
            }
#pragma unroll
            for (int j = 0; j < 4; ++j) {
                int qq = wid + 4*j;
                const float4* qp = (const float4*)&Qs[qq][0] + half*4;
                float s0 = 0.f;
#pragma unroll
                for (int c = 0; c < 4; ++c) {
                    float4 q4 = qp[c];
                    s0 += q4.x*kf[c].x + q4.y*kf[c].y + q4.z*kf[c].z + q4.w*kf[c].w;
                }
                lv[j] += s0;
            }
            if (half == 0) __builtin_amdgcn_sched_barrier(0);
        }
#pragma unroll
        for (int j = 0; j < 4; ++j) lv[j] = lv[j] * fm[j] * SCALE_INV;

        // 4 independent max butterflies
        float mloc[4];
#pragma unroll
        for (int j = 0; j < 4; ++j) mloc[j] = lv[j];
#pragma unroll
        for (int off = 1; off < 64; off <<= 1)
#pragma unroll
            for (int j = 0; j < 4; ++j)
                mloc[j] = fmaxf(mloc[j], __shfl_xor(mloc[j], off, 64));

#pragma unroll
        for (int j = 0; j < 4; ++j) {
            int qq = wid + 4*j;
            float mnew  = fmaxf(m[j], mloc[j]);
            float alpha = __expf(m[j] - mnew);
            float p     = __expf(lv[j] - mnew);
            s[j] = s[j]*alpha + p;         // per-lane partial sum
            m[j] = mnew;
            As[qq][kcol] = p;
            if (kcol == 0) As[qq][64] = alpha;
        }
        __syncthreads();

        // prefetch next tile's fused multiplier while PV runs
        if (kt + 1 < 32) {
            const int kgn = (kt+1)*64 + kcol;
#pragma unroll
            for (int j = 0; j < 4; ++j) {
                size_t mi = (mrow + wid + 4*j) * LL + kgn;
                int   mk = mask[mi];
                float a  = adj[mi];
                float d  = dist[mi];
                fm[j] = (mk == 1) ? (1.0f + a*wa + d*wd) : 0.0f;
            }
        }

        // PV: thread (grp,dcol) accumulates rows grp*2..+1, d = dcol
        float sum[2] = {0.f, 0.f};
#pragma unroll
        for (int c = 0; c < 16; ++c) {
            int kl = c * 4;
            float v0 = Vs[kl+0][dcol];
            float v1 = Vs[kl+1][dcol];
            float v2 = Vs[kl+2][dcol];
            float v3 = Vs[kl+3][dcol];
#pragma unroll
            for (int jj = 0; jj < 2; ++jj) {
                float4 a4 = *(const float4*)&As[grp*2+jj][kl];
                sum[jj] += a4.x*v0 + a4.y*v1 + a4.z*v2 + a4.w*v3;
            }
        }
#pragma unroll
        for (int jj = 0; jj < 2; ++jj) {
            int r = grp*2 + jj;
            acc[jj] = acc[jj]*As[r][64] + sum[jj];
        }
        __syncthreads();
    }

    // epilogue: one sum butterfly per row; stats out; ctx scale
#pragma unroll
    for (int j = 0; j < 4; ++j) {
        float ss = s[j];
#pragma unroll
        for (int off = 1; off < 64; off <<= 1)
            ss += __shfl_xor(ss, off, 64);
        float inv = 1.0f / ss;
        int qq = wid + 4*j;
        int qg = q0 + qq;
        if (kcol == 0) {
            As[qq][65] = inv;
            if (bh != 15) { Mall[bh*LL + qg] = m[j]; Sall[bh*LL + qg] = inv; }
            else          { Mw[qg] = m[j];           Sw[qg] = inv; }
        }
    }
    __syncthreads();

#pragma unroll
    for (int jj = 0; jj < 2; ++jj) {
        int r  = grp*2 + jj;
        int qg = q0 + r;
        ctx[(size_t)(bh * LL + qg) * DHEAD + dcol] = acc[jj] * As[r][65];
    }
}

// ---------------- Kernel 3: attn finalize for bh 0..14 — recompute + single write ----
// grid (64, 8, 15). Reads Qw/Kw (L2-resident), M/S stats, recomputes logits,
// writes the final softmax value ONCE.
__global__ __launch_bounds__(256) void attn_final_kernel(
    const float* __restrict__ Q, const float* __restrict__ K,
    const int* __restrict__ mask, const float* __restrict__ adj, const float* __restrict__ dist,
    const float* __restrict__ wA, const float* __restrict__ wD,
    const float* __restrict__ Mall, const float* __restrict__ Sall,
    float* __restrict__ attn)
{
    const int t    = threadIdx.x;
    const int bh   = blockIdx.z;          // 0..14
    const int b    = bh >> 3;
    const int h    = bh & 7;
    const int q0   = blockIdx.x * 32;
    const int kt0  = blockIdx.y * 2;
    const int kcol = t & 63;
    const int wid  = t >> 6;

    __shared__ float Qs[32][36];
    __shared__ float Ks[128][36];

    const float wa = wA[h];
    const float wd = wD[h];

    const size_t qk_base = (size_t)bh * LL * DHEAD;
    float* aout = attn + (size_t)bh * LL2;

    {
        int row = t >> 3;
        int c   = (t & 7) << 2;
        float4 qv = *(const float4*)(Q + qk_base + (size_t)(q0 + row) * DHEAD + c);
        Qs[row][c+0] = qv.x; Qs[row][c+1] = qv.y; Qs[row][c+2] = qv.z; Qs[row][c+3] = qv.w;
    }

    float Mr[8], Sr[8];
#pragma unroll
    for (int j = 0; j < 8; ++j) {
        int qg = q0 + wid + 4*j;
        Mr[j] = Mall[bh*LL + qg];
        Sr[j] = Sall[bh*LL + qg];
    }

    for (int kt = kt0; kt < kt0 + 2; ++kt) {
#pragma unroll
        for (int r = 0; r < 4; ++r) {
            int f   = t + 256 * r;
            int row = f >> 3;
            int c   = (f & 7) << 2;
            float4 kv = *(const float4*)(K + qk_base + (size_t)(kt*128 + row) * DHEAD + c);
            Ks[row][c+0]=kv.x; Ks[row][c+1]=kv.y; Ks[row][c+2]=kv.z; Ks[row][c+3]=kv.w;
        }
        __syncthreads();

        float4 k0[8], k1[8];
        {
            const float4* p0 = (const float4*)&Ks[kcol][0];
            const float4* p1 = (const float4*)&Ks[kcol + 64][0];
#pragma unroll
            for (int c = 0; c < 8; ++c) { k0[c] = p0[c]; k1[c] = p1[c]; }
        }

        const int kg0 = kt*128 + kcol;
#pragma unroll
        for (int j = 0; j < 8; ++j) {
            int qq = wid + 4*j;
            float s0 = 0.f, s1 = 0.f;
            const float4* qp = (const float4*)&Qs[qq][0];
#pragma unroll
            for (int c = 0; c < 8; ++c) {
                float4 q4 = qp[c];
                s0 += q4.x*k0[c].x + q4.y*k0[c].y + q4.z*k0[c].z + q4.w*k0[c].w;
                s1 += q4.x*k1[c].x + q4.y*k1[c].y + q4.z*k1[c].z + q4.w*k1[c].w;
            }
            int qg = q0 + qq;
            size_t mi0 = (size_t)(b * LL + qg) * LL + kg0;
            size_t mi1 = mi0 + 64;
            float fm0 = (mask[mi0] == 1) ? (1.0f + adj[mi0]*wa + dist[mi0]*wd) : 0.0f;
            float fm1 = (mask[mi1] == 1) ? (1.0f + adj[mi1]*wa + dist[mi1]*wd) : 0.0f;
            float l0 = s0 * fm0 * SCALE_INV;
            float l1 = s1 * fm1 * SCALE_INV;
            size_t ai = (size_t)qg * LL + kg0;
            aout[ai]      = __expf(l0 - Mr[j]) * Sr[j];
            aout[ai + 64] = __expf(l1 - Mr[j]) * Sr[j];
        }
        __syncthreads();
    }
}

// ---------------- Kernel 4: output projection ----------------
__global__ __launch_bounds__(256) void out_gemm_kernel(
    const float* __restrict__ ctx, const float* __restrict__ Wo, float* __restrict__ Y)
{
    __shared__ float Xs[64][33];
    __shared__ float Ws[64][33];

    const int t  = threadIdx.x;
    const int m0 = blockIdx.x * 64;
    const int n0 = blockIdx.y * 64;
    const int ty = t >> 4;
    const int tx = t & 15;

    float acc[4][4] = {};

    for (int kt = 0; kt < 8; ++kt) {
#pragma unroll
        for (int r = 0; r < 2; ++r) {
            int f   = t + 256*r;
            int row = f >> 3;
            int c   = (f & 7) << 2;
            int grow = m0 + row;
            int b = grow / LL, l = grow % LL;
            float4 xv4 = *(const float4*)(ctx + (size_t)((b*NH + kt)*LL + l) * DHEAD + c);
            Xs[row][c+0]=xv4.x; Xs[row][c+1]=xv4.y; Xs[row][c+2]=xv4.z; Xs[row][c+3]=xv4.w;
            float4 wv4 = *(const float4*)(Wo + (size_t)(n0 + row) * DMODEL + kt*32 + c);
            Ws[row][c+0]=wv4.x; Ws[row][c+1]=wv4.y; Ws[row][c+2]=wv4.z; Ws[row][c+3]=wv4.w;
        }
        __syncthreads();
#pragma unroll
        for (int kk = 0; kk < 32; ++kk) {
            float a[4], bv[4];
#pragma unroll
            for (int i = 0; i < 4; ++i) a[i]  = Xs[ty*4+i][kk];
#pragma unroll
            for (int j = 0; j < 4; ++j) bv[j] = Ws[tx*4+j][kk];
#pragma unroll
            for (int i = 0; i < 4; ++i)
#pragma unroll
                for (int j = 0; j < 4; ++j)
                    acc[i][j] = fmaf(a[i], bv[j], acc[i][j]);
        }
        __syncthreads();
    }

#pragma unroll
    for (int i = 0; i < 4; ++i) {
        int row = m0 + ty*4 + i;
#pragma unroll
        for (int j = 0; j < 4; ++j) {
            int col = n0 + tx*4 + j;
            Y[(size_t)row * DMODEL + col] = acc[i][j];
        }
    }
}

// ---------------- Kernel 5: attn writes for bh==15, split-k ----------------
// grid (64, 8). Runs LAST (clobbers scratch parked in the bh=15 slab).
__global__ __launch_bounds__(256) void attn15_kernel(
    const float* __restrict__ Q15, const float* __restrict__ K15,
    const int* __restrict__ mask, const float* __restrict__ adj, const float* __restrict__ dist,
    const float* __restrict__ wA, const float* __restrict__ wD,
    const float* __restrict__ Mw, const float* __restrict__ Sw,
    float* __restrict__ attn15)
{
    const int t    = threadIdx.x;
    const int q0   = blockIdx.x * 32;
    const int kt0  = blockIdx.y * 2;
    const int kcol = t & 63;
    const int wid  = t >> 6;

    __shared__ float Qs[32][36];
    __shared__ float Ks[128][36];

    const float wa = wA[7];
    const float wd = wD[7];

    {
        int row = t >> 3;
        int c   = (t & 7) << 2;
        float4 qv = *(const float4*)(Q15 + (size_t)(q0 + row) * DHEAD + c);
        Qs[row][c+0] = qv.x; Qs[row][c+1] = qv.y; Qs[row][c+2] = qv.z; Qs[row][c+3] = qv.w;
    }

    float Mr[8], Sr[8];
#pragma unroll
    for (int j = 0; j < 8; ++j) {
        int qg = q0 + wid + 4*j;
        Mr[j] = Mw[qg];
        Sr[j] = Sw[qg];
    }

    for (int kt = kt0; kt < kt0 + 2; ++kt) {
#pragma unroll
        for (int r = 0; r < 4; ++r) {
            int f   = t + 256 * r;
            int row = f >> 3;
            int c   = (f & 7) << 2;
            float4 kv = *(const float4*)(K15 + (size_t)(kt*128 + row) * DHEAD + c);
            Ks[row][c+0]=kv.x; Ks[row][c+1]=kv.y; Ks[row][c+2]=kv.z; Ks[row][c+3]=kv.w;
        }
        __syncthreads();

        float4 k0[8], k1[8];
        {
            const float4* p0 = (const float4*)&Ks[kcol][0];
            const float4* p1 = (const float4*)&Ks[kcol + 64][0];
#pragma unroll
            for (int c = 0; c < 8; ++c) { k0[c] = p0[c]; k1[c] = p1[c]; }
        }

        const int kg0 = kt*128 + kcol;
#pragma unroll
        for (int j = 0; j < 8; ++j) {
            int qq = wid + 4*j;
            float s0 = 0.f, s1 = 0.f;
            const float4* qp = (const float4*)&Qs[qq][0];
#pragma unroll
            for (int c = 0; c < 8; ++c) {
                float4 q4 = qp[c];
                s0 += q4.x*k0[c].x + q4.y*k0[c].y + q4.z*k0[c].z + q4.w*k0[c].w;
                s1 += q4.x*k1[c].x + q4.y*k1[c].y + q4.z*k1[c].z + q4.w*k1[c].w;
            }
            int qg = q0 + qq;
            size_t mi0 = (size_t)(LL + qg) * LL + kg0;      // b = 1
            size_t mi1 = mi0 + 64;
            float sm0 = (mask[mi0] == 1) ? s0 : 0.0f;
            float sm1 = (mask[mi1] == 1) ? s1 : 0.0f;
            float l0 = sm0 * (1.0f + adj[mi0]*wa + dist[mi0]*wd) * SCALE_INV;
            float l1 = sm1 * (1.0f + adj[mi1]*wa + dist[mi1]*wd) * SCALE_INV;
            size_t ai = (size_t)qg * LL + kg0;
            attn15[ai]      = __expf(l0 - Mr[j]) * Sr[j];
            attn15[ai + 64] = __expf(l1 - Mr[j]) * Sr[j];
        }
        __syncthreads();
    }
}

extern "C" void kernel_launch(void* const* d_in, const int* in_sizes, int n_in,
                              void* d_out, int out_size, void* d_ws, size_t ws_size,
                              hipStream_t stream)
{
    const float* q    = (const float*)d_in[0];
    const float* k    = (const float*)d_in[1];
    const float* v    = (const float*)d_in[2];
    const int*   mask = (const int*)d_in[3];
    const float* adj  = (const float*)d_in[4];
    const float* dist = (const float*)d_in[5];
    const float* Wq   = (const float*)d_in[6];
    const float* Wk   = (const float*)d_in[7];
    const float* Wv   = (const float*)d_in[8];
    const float* Wo   = (const float*)d_in[9];
    const float* wA   = (const float*)d_in[10];
    const float* wD   = (const float*)d_in[11];

    float* out  = (float*)d_out;                       // B*L*DM = 1,048,576 floats
    float* attn = out + (size_t)BB*LL*DMODEL;          // B*H*L*L

    // Scratch parked in attn[bh=15]'s slab (4*NQ floats = 16 MB, dead until attn15).
    float* tail = attn + (size_t)15 * LL2;
    float* Qw = tail;
    float* Kw = tail + (size_t)NQ;
    float* Vw = tail + (size_t)2 * NQ;
    float* Cw = tail + (size_t)3 * NQ;

    // Softmax stats (bh<15) parked in `out` (dead until out_gemm; attn_final
    // consumes them BEFORE out_gemm runs).
    float* Mall = out;                 // 15*2048 floats
    float* Sall = out + 32768;         // 15*2048 floats

    // Tiny ws: bh=15 Q/K slices + bh=15 stats (528 KB).
    float* Q15 = (float*)d_ws;
    float* K15 = Q15 + (size_t)LL * DHEAD;
    float* Mw  = K15 + (size_t)LL * DHEAD;
    float* Sw  = Mw + LL;

    dim3 g1(64, 4, 3);
    proj_kernel<<<g1, 256, 0, stream>>>(q, k, v, Wq, Wk, Wv, Qw, Kw, Vw, Q15, K15);

    dim3 g2(LL/16, BB*NH);
    attn_main_kernel<<<g2, 256, 0, stream>>>(Qw, Kw, Vw, mask, adj, dist, wA, wD,
                                             Cw, Mall, Sall, Mw, Sw);

    // bh<15 attn: recompute + single write (reads Qw/Kw + Mall/Sall in `out`)
    dim3 gf(64, 8, 15);
    attn_final_kernel<<<gf, 256, 0, stream>>>(Qw, Kw, mask, adj, dist, wA, wD,
                                              Mall, Sall, attn);

    // out projection (overwrites `out`, consumes Cw)
    dim3 g3(64, 4);
    out_gemm_kernel<<<g3, 256, 0, stream>>>(Cw, Wo, out);

    // bh=15 attn last (clobbers scratch slab; reads ws duplicates)
    dim3 g4(64, 8);
    attn15_kernel<<<g4, 256, 0, stream>>>(Q15, K15, mask, adj, dist, wA, wD, Mw, Sw,
                                          attn + (size_t)15 * LL2);
}